// Round 3
// baseline (735.683 us; speedup 1.0000x reference)
//
#include <hip/hip_runtime.h>

// Linear_6983616824492: e3nn-style irrep linear, B=50000, blocks (mul,d):
// (256,1)@off0, (256,3)@off256, (128,5)@off1024, row = 1664 fp32.
// v3 (resubmit — round-2 bench was an infra failure, not a kernel verdict):
// multi-tile pipelined WGs (T14 async-STAGE split). v2 fixed the scattered-A
// request-rate problem with coalesced->LDS staging, but each WG did
// stage -> sync -> compute -> exit: every tile pays full HBM latency
// serially. Now each WG owns 5 consecutive 16-row tiles; while computing
// tile t it issues tile t+1's coalesced float4 loads into registers, then
// converts+writes to the (single, XOR-swizzled) LDS buffer after the
// post-compute barrier. HBM latency hides under the MFMA/B-load phase.
// B operand (prep-swizzled bf16 in d_ws, L2-resident), fragment repack and
// store epilogue unchanged from the verified v2.

typedef __attribute__((ext_vector_type(8))) short short8;   // 8 bf16 (4 VGPRs)
typedef __attribute__((ext_vector_type(4))) float f32x4;    // MFMA C/D frag

#define NBATCH 50000
#define NTOTAL 1664

__device__ __forceinline__ unsigned short f2bf(float f) {
    union { float f; unsigned u; } v; v.f = f;
    unsigned r = v.u + 0x7fffu + ((v.u >> 16) & 1u);  // round-nearest-even
    return (unsigned short)(r >> 16);
}

// ---------------- prep: swizzled bf16 B operands into workspace -------------
// Per block, flat element e: j = e&7, lane = (e>>3)&63, qt = e>>9,
// t = qt % NT, q = qt / NT.  value = bf16(W[(q*32 + (lane>>4)*8 + j)*N
//                                          + t*16 + (lane&15)])
// Main kernel loads short8 at index (q*NT + t)*64 + lane (1KB/wave instr,
// L2-resident: 288KB total).
__global__ void prep_kernel(const float* __restrict__ w0,
                            const float* __restrict__ w1,
                            const float* __restrict__ w2,
                            unsigned short* __restrict__ ws) {
    int e = blockIdx.x * blockDim.x + threadIdx.x;
    const float* W; int N, base;
    if (e < 65536)       { W = w0; N = 256; base = 0; }
    else if (e < 131072) { W = w1; N = 256; base = 65536;  e -= 65536; }
    else if (e < 147456) { W = w2; N = 128; base = 131072; e -= 131072; }
    else return;
    int j = e & 7;
    int lane = (e >> 3) & 63;
    int qt = e >> 9;
    int NT = N >> 4;
    int t = qt % NT;
    int q = qt / NT;
    int u = q * 32 + ((lane >> 4) << 3) + j;
    int w = t * 16 + (lane & 15);
    ws[base + e] = f2bf(W[u * N + w]);
}

// ---------------- main kernel ----------------------------------------------
// D = irrep dim, K = mul (contraction), NT = total 16-wide w-tiles,
// NTW = w-tiles per wave (NT/4), OFF = column offset, TP = tiles per WG.
// MFMA 16x16x32_bf16 layouts (HW-verified per guide):
//   A: lane holds A[m=lane&15][k=(lane>>4)*8+j]
//   B: lane holds B[k=(lane>>4)*8+j][n=lane&15]
//   C/D: reg r holds C[row=(lane>>4)*4+r][col=lane&15]
template<int D, int K, int NT, int NTW, int OFF, int TP>
__device__ __forceinline__ void run_block(const float* __restrict__ x,
                                          float* __restrict__ out,
                                          const short8* __restrict__ bsw,
                                          float pw,
                                          char* __restrict__ sm) {
    constexpr int COLS   = K * D;            // fp32 elems per row, this block
    constexpr int C4     = COLS / 4;         // float4 chunks per row
    constexpr int RB     = COLS * 2;         // LDS row stride, bytes (bf16)
    constexpr int ROUNDS = (16 * C4) / 256;  // stage rounds for 256 threads

    const int tid  = threadIdx.x;
    const int lane = tid & 63;
    const int wave = tid >> 6;
    const int tile0 = blockIdx.x * TP;

    // ---- prefetch: coalesced global float4 loads into registers ----
    float4 pf[ROUNDS];
    auto load_pf = [&](int tile) {
#pragma unroll
        for (int rr = 0; rr < ROUNDS; ++rr) {
            int c    = rr * 256 + tid;
            int row  = c / C4;          // compile-time-constant divisor
            int col4 = c - row * C4;
            pf[rr] = *((const float4*)
                       (x + (size_t)(tile * 16 + row) * NTOTAL + OFF) + col4);
        }
    };
    // ---- convert + write to XOR-swizzled LDS ----
    // RB % 128 == 0 for all blocks: without the bit-4..6 XOR all 16 rows
    // alias the same banks on the b128 fragment reads.
    auto write_lds = [&]() {
#pragma unroll
        for (int rr = 0; rr < ROUNDS; ++rr) {
            int c    = rr * 256 + tid;
            int row  = c / C4;
            int col4 = c - row * C4;
            float4 v = pf[rr];
            unsigned long long pk =
                  (unsigned long long)f2bf(v.x)
                | ((unsigned long long)f2bf(v.y) << 16)
                | ((unsigned long long)f2bf(v.z) << 32)
                | ((unsigned long long)f2bf(v.w) << 48);
            *(unsigned long long*)(sm + row * RB
                                   + ((col4 * 8) ^ ((row & 7) << 4))) = pk;
        }
    };

    load_pf(tile0);
    write_lds();
    __syncthreads();

    const int bcol = lane & 15;   // A row (m) / C col (n)
    const int quad = lane >> 4;
    const char* lrow = sm + bcol * RB;
    const int sw = (bcol & 7) << 4;

    for (int t = 0; t < TP; ++t) {
        // issue next tile's global loads NOW; latency hides under compute
        if (t + 1 < TP) load_pf(tile0 + t + 1);

        f32x4 acc[NTW][D];
#pragma unroll
        for (int tt = 0; tt < NTW; ++tt)
#pragma unroll
            for (int i = 0; i < D; ++i)
                acc[tt][i] = (f32x4){0.f, 0.f, 0.f, 0.f};

#pragma unroll
        for (int q = 0; q < K / 32; ++q) {
            // lane's 8*D consecutive bf16: D b128 reads, then stride-D repack
            const int cb = (q * 32 + quad * 8) * D * 2;   // multiple of 16
            short8 raw[D];
#pragma unroll
            for (int m = 0; m < D; ++m)
                raw[m] = *(const short8*)(lrow + ((cb + m * 16) ^ sw));

            short8 af[D];
#pragma unroll
            for (int i = 0; i < D; ++i)
#pragma unroll
                for (int j = 0; j < 8; ++j) {
                    const int e = j * D + i;
                    af[i][j] = raw[e >> 3][e & 7];
                }

#pragma unroll
            for (int tt = 0; tt < NTW; ++tt) {
                const int tw = wave * NTW + tt;
                short8 bf = bsw[(q * NT + tw) * 64 + lane];
#pragma unroll
                for (int i = 0; i < D; ++i)
                    acc[tt][i] = __builtin_amdgcn_mfma_f32_16x16x32_bf16(
                        af[i], bf, acc[tt][i], 0, 0, 0);
            }
        }

        // epilogue: y[b0+quad*4+r][OFF + (tw*16+bcol)*D + i] = pw * acc
        const int b0 = (tile0 + t) << 4;
#pragma unroll
        for (int tt = 0; tt < NTW; ++tt) {
            const int wcol = (wave * NTW + tt) * 16 + bcol;
#pragma unroll
            for (int r = 0; r < 4; ++r) {
                float* op = out + (size_t)(b0 + quad * 4 + r) * NTOTAL + OFF
                            + wcol * D;
#pragma unroll
                for (int i = 0; i < D; ++i)
                    op[i] = acc[tt][i][r] * pw;
            }
        }

        __syncthreads();                 // all waves done reading LDS tile t
        if (t + 1 < TP) {
            write_lds();                 // vmcnt wait happens here, post-hide
            __syncthreads();
        }
    }
}

__global__ __launch_bounds__(256, 3)
void linear_kernel(const float* __restrict__ x, float* __restrict__ out,
                   const unsigned short* __restrict__ ws) {
    // max LDS need: block1 = 16 rows * 768 bf16 = 24576 B (single buffer)
    __shared__ __attribute__((aligned(16))) char sm[24576];
    const short8* bs0 = (const short8*)(ws);
    const short8* bs1 = (const short8*)(ws + 65536);
    const short8* bs2 = (const short8*)(ws + 131072);
    if (blockIdx.y == 0)
        run_block<1, 256, 16, 4, 0, 5>(x, out, bs0, 0.0625f, sm);
    else if (blockIdx.y == 1)
        run_block<3, 256, 16, 4, 256, 5>(x, out, bs1, 0.0625f, sm);
    else
        run_block<5, 128, 8, 2, 1024, 5>(x, out, bs2,
                                         0.08838834764831845f, sm);
}

extern "C" void kernel_launch(void* const* d_in, const int* in_sizes, int n_in,
                              void* d_out, int out_size, void* d_ws,
                              size_t ws_size, hipStream_t stream) {
    const float* x  = (const float*)d_in[0];
    const float* w0 = (const float*)d_in[1];
    const float* w1 = (const float*)d_in[2];
    const float* w2 = (const float*)d_in[3];
    unsigned short* ws = (unsigned short*)d_ws;  // needs 294912 B

    prep_kernel<<<dim3(576), 256, 0, stream>>>(w0, w1, w2, ws);

    dim3 grid(NBATCH / 16 / 5, 3);  // 50000 = 625 * 5 * 16 exactly
    linear_kernel<<<grid, 256, 0, stream>>>(x, (float*)d_out, ws);
}

// Round 4
// 713.401 us; speedup vs baseline: 1.0312x; 1.0312x over previous
//
#include <hip/hip_runtime.h>

// Linear_6983616824492: e3nn-style irrep linear, B=50000, blocks (mul,d):
// (256,1)@off0, (256,3)@off256, (128,5)@off1024, row = 1664 fp32.
// v4: vmcnt-clean pipelined WGs. v3 regressed from (a) scratch spill --
// FETCH/WRITE each grew ~170 MB symmetrically, VGPR capped at 84 while
// pf(48)+acc(48) were live across the whole compute -- and (b) vmcnt FIFO
// ordering: prefetch HBM loads issued before the q-loop forced every
// B-fragment wait to drain them. Fixes:
//   1. prefetch issued AFTER all B loads of the tile (post-compute,
//      pre-epilogue, pinned by sched_barrier) -> short pf liveness, and
//      B waits never queue behind HBM prefetch.
//   2. lgkm-only barrier (raw s_barrier) between epilogue and LDS
//      overwrite so the pf loads stay in flight across it; the full
//      __syncthreads (vmcnt drain) comes only after pf is consumed.
//   3. amdgpu_waves_per_eu(3,4): forbid the allocator's
//      spill-for-occupancy heuristic (v3's 84-VGPR+scratch choice).
//   4. grid-stride tiles (1042 WGs/y, ~3 tiles each): prologue amortized,
//      small launch tail.
// Stage math, XOR swizzle, fragment repack, B path, epilogue: byte-identical
// to the verified v2.

typedef __attribute__((ext_vector_type(8))) short short8;   // 8 bf16 (4 VGPRs)
typedef __attribute__((ext_vector_type(4))) float f32x4;    // MFMA C/D frag

#define NBATCH 50000
#define NTOTAL 1664
#define NTILES 3125      // 50000 / 16
#define GRIDX  1042      // ceil(3125/3): each WG handles 2-3 tiles

__device__ __forceinline__ unsigned short f2bf(float f) {
    union { float f; unsigned u; } v; v.f = f;
    unsigned r = v.u + 0x7fffu + ((v.u >> 16) & 1u);  // round-nearest-even
    return (unsigned short)(r >> 16);
}

// ---------------- prep: swizzled bf16 B operands into workspace -------------
// Per block, flat element e: j = e&7, lane = (e>>3)&63, qt = e>>9,
// t = qt % NT, q = qt / NT.  value = bf16(W[(q*32 + (lane>>4)*8 + j)*N
//                                          + t*16 + (lane&15)])
// Main kernel loads short8 at index (q*NT + t)*64 + lane (1KB/wave instr,
// L2-resident: 288KB total).
__global__ void prep_kernel(const float* __restrict__ w0,
                            const float* __restrict__ w1,
                            const float* __restrict__ w2,
                            unsigned short* __restrict__ ws) {
    int e = blockIdx.x * blockDim.x + threadIdx.x;
    const float* W; int N, base;
    if (e < 65536)       { W = w0; N = 256; base = 0; }
    else if (e < 131072) { W = w1; N = 256; base = 65536;  e -= 65536; }
    else if (e < 147456) { W = w2; N = 128; base = 131072; e -= 131072; }
    else return;
    int j = e & 7;
    int lane = (e >> 3) & 63;
    int qt = e >> 9;
    int NT = N >> 4;
    int t = qt % NT;
    int q = qt / NT;
    int u = q * 32 + ((lane >> 4) << 3) + j;
    int w = t * 16 + (lane & 15);
    ws[base + e] = f2bf(W[u * N + w]);
}

// ---------------- main kernel ----------------------------------------------
// D = irrep dim, K = mul (contraction), NT = total 16-wide w-tiles,
// NTW = w-tiles per wave (NT/4), OFF = column offset of this block.
// MFMA 16x16x32_bf16 layouts (HW-verified per guide):
//   A: lane holds A[m=lane&15][k=(lane>>4)*8+j]
//   B: lane holds B[k=(lane>>4)*8+j][n=lane&15]
//   C/D: reg r holds C[row=(lane>>4)*4+r][col=lane&15]
template<int D, int K, int NT, int NTW, int OFF>
__device__ __forceinline__ void run_block(const float* __restrict__ x,
                                          float* __restrict__ out,
                                          const short8* __restrict__ bsw,
                                          float pw, char* __restrict__ sm,
                                          int tile) {
    constexpr int COLS   = K * D;            // fp32 elems per row, this block
    constexpr int C4     = COLS / 4;         // float4 chunks per row
    constexpr int RB     = COLS * 2;         // LDS row stride, bytes (bf16)
    constexpr int ROUNDS = (16 * C4) / 256;  // stage rounds for 256 threads

    const int tid  = threadIdx.x;
    const int lane = tid & 63;
    const int wave = tid >> 6;

    float4 pf[ROUNDS];
    auto ld_pf = [&](int t) {
#pragma unroll
        for (int rr = 0; rr < ROUNDS; ++rr) {
            int c    = rr * 256 + tid;
            int row  = c / C4;          // compile-time-constant divisor
            int col4 = c - row * C4;
            pf[rr] = *((const float4*)
                       (x + (size_t)(t * 16 + row) * NTOTAL + OFF) + col4);
        }
    };
    // convert + write to XOR-swizzled LDS. RB % 128 == 0 for all blocks:
    // without the bit-4..6 XOR all 16 rows alias the same banks on the
    // b128 fragment reads.
    auto cvt_write = [&]() {
#pragma unroll
        for (int rr = 0; rr < ROUNDS; ++rr) {
            int c    = rr * 256 + tid;
            int row  = c / C4;
            int col4 = c - row * C4;
            float4 v = pf[rr];
            unsigned long long pk =
                  (unsigned long long)f2bf(v.x)
                | ((unsigned long long)f2bf(v.y) << 16)
                | ((unsigned long long)f2bf(v.z) << 32)
                | ((unsigned long long)f2bf(v.w) << 48);
            *(unsigned long long*)(sm + row * RB
                                   + ((col4 * 8) ^ ((row & 7) << 4))) = pk;
        }
    };

    // prologue: stage first tile (full __syncthreads is fine here)
    ld_pf(tile);
    cvt_write();
    __syncthreads();

    const int bcol = lane & 15;   // A row (m) / C col (n)
    const int quad = lane >> 4;
    const char* lrow = sm + bcol * RB;
    const int sw = (bcol & 7) << 4;

    while (true) {
        f32x4 acc[NTW][D];
#pragma unroll
        for (int tt = 0; tt < NTW; ++tt)
#pragma unroll
            for (int i = 0; i < D; ++i)
                acc[tt][i] = (f32x4){0.f, 0.f, 0.f, 0.f};

#pragma unroll
        for (int q = 0; q < K / 32; ++q) {
            // lane's 8*D consecutive bf16: D b128 reads, then stride-D repack
            const int cb = (q * 32 + quad * 8) * D * 2;   // multiple of 16
            short8 raw[D];
#pragma unroll
            for (int m = 0; m < D; ++m)
                raw[m] = *(const short8*)(lrow + ((cb + m * 16) ^ sw));

            short8 af[D];
#pragma unroll
            for (int i = 0; i < D; ++i)
#pragma unroll
                for (int j = 0; j < 8; ++j) {
                    const int e = j * D + i;
                    af[i][j] = raw[e >> 3][e & 7];
                }

#pragma unroll
            for (int tt = 0; tt < NTW; ++tt) {
                const int tw = wave * NTW + tt;
                short8 bf = bsw[(q * NT + tw) * 64 + lane];
#pragma unroll
                for (int i = 0; i < D; ++i)
                    acc[tt][i] = __builtin_amdgcn_mfma_f32_16x16x32_bf16(
                        af[i], bf, acc[tt][i], 0, 0, 0);
            }
        }

        const int nxt  = tile + GRIDX;
        const bool more = nxt < NTILES;   // WG-uniform

        // issue next tile's HBM loads strictly AFTER all B loads (vmcnt is
        // FIFO: pf ahead of B-frag loads would stall every MFMA on HBM).
        __builtin_amdgcn_sched_barrier(0);
        if (more) ld_pf(nxt);
        __builtin_amdgcn_sched_barrier(0);

        // epilogue stores overlap the pf latency:
        // y[b0+quad*4+r][OFF + (tw*16+bcol)*D + i] = pw * acc
        const int b0 = tile << 4;
#pragma unroll
        for (int tt = 0; tt < NTW; ++tt) {
            const int wcol = (wave * NTW + tt) * 16 + bcol;
#pragma unroll
            for (int r = 0; r < 4; ++r) {
                float* op = out + (size_t)(b0 + quad * 4 + r) * NTOTAL + OFF
                            + wcol * D;
#pragma unroll
                for (int i = 0; i < D; ++i)
                    op[i] = acc[tt][i][r] * pw;
            }
        }

        if (!more) break;

        // read-drain barrier: lgkm only -- pf global loads stay in flight.
        // (Full __syncthreads here would vmcnt(0)-drain them = v2's serial
        // stall. All ds_read results are already consumed into registers.)
        asm volatile("s_waitcnt lgkmcnt(0)" ::: "memory");
        __builtin_amdgcn_s_barrier();
        __builtin_amdgcn_sched_barrier(0);

        cvt_write();          // counted vmcnt waits per round, then ds_write
        __syncthreads();      // writes visible to all waves; pf consumed
        tile = nxt;
    }
}

__attribute__((amdgpu_waves_per_eu(3, 4)))
__global__ __launch_bounds__(256)
void linear_kernel(const float* __restrict__ x, float* __restrict__ out,
                   const unsigned short* __restrict__ ws) {
    // max LDS: block1 = 16 rows * 768 bf16 = 24576 B (single buffer)
    __shared__ __attribute__((aligned(16))) char sm[24576];
    const short8* bs0 = (const short8*)(ws);
    const short8* bs1 = (const short8*)(ws + 65536);
    const short8* bs2 = (const short8*)(ws + 131072);
    if (blockIdx.y == 0)
        run_block<1, 256, 16, 4, 0>(x, out, bs0, 0.0625f, sm, blockIdx.x);
    else if (blockIdx.y == 1)
        run_block<3, 256, 16, 4, 256>(x, out, bs1, 0.0625f, sm, blockIdx.x);
    else
        run_block<5, 128, 8, 2, 1024>(x, out, bs2, 0.08838834764831845f, sm,
                                      blockIdx.x);
}

extern "C" void kernel_launch(void* const* d_in, const int* in_sizes, int n_in,
                              void* d_out, int out_size, void* d_ws,
                              size_t ws_size, hipStream_t stream) {
    const float* x  = (const float*)d_in[0];
    const float* w0 = (const float*)d_in[1];
    const float* w1 = (const float*)d_in[2];
    const float* w2 = (const float*)d_in[3];
    unsigned short* ws = (unsigned short*)d_ws;  // needs 294912 B

    prep_kernel<<<dim3(576), 256, 0, stream>>>(w0, w1, w2, ws);

    dim3 grid(GRIDX, 3);
    linear_kernel<<<grid, 256, 0, stream>>>(x, (float*)d_out, ws);
}

// Round 5
// 560.259 us; speedup vs baseline: 1.3131x; 1.2733x over previous
//
#include <hip/hip_runtime.h>

// Linear_6983616824492: e3nn-style irrep linear, B=50000, blocks (mul,d):
// (256,1)@off0, (256,3)@off256, (128,5)@off1024, row = 1664 fp32.
// v5: kill the scratch spill by governing occupancy through LDS size.
// v3/v4 post-mortem: VGPR_Count=84 (=512/6) with ~390 MB of symmetric
// extra FETCH+WRITE -- the allocator targets 6 waves/EU because 24576 B
// of LDS permits 6 WGs/CU, and spills the pf+acc working set (~116 regs)
// to scratch to get there. launch_bounds' 2nd arg is only a VGPR ceiling,
// and amdgpu_waves_per_eu was ignored (84 regs is outside its stated max).
// Fix: pad static LDS to 48 KiB -> max 3 WGs/CU -> allocator's own target
// becomes 3 waves/EU -> VGPR budget 170 >> ~116 need -> no spill. 12
// waves/CU is the occupancy v1 ran at, and MLP is over-provisioned
// (12 waves x 12 in-flight float4 wave-loads covers HBM latency ~16x).
// Pipeline structure (vmcnt-clean: pf issued AFTER all B loads; lgkm-only
// barrier keeps pf in flight across the LDS-overwrite sync), stage math,
// XOR swizzle, fragment repack, B path, epilogue: identical to v4 (passed).

typedef __attribute__((ext_vector_type(8))) short short8;   // 8 bf16 (4 VGPRs)
typedef __attribute__((ext_vector_type(4))) float f32x4;    // MFMA C/D frag

#define NBATCH 50000
#define NTOTAL 1664
#define NTILES 3125      // 50000 / 16
#define GRIDX  1042      // ceil(3125/3): each WG handles 2-3 tiles

__device__ __forceinline__ unsigned short f2bf(float f) {
    union { float f; unsigned u; } v; v.f = f;
    unsigned r = v.u + 0x7fffu + ((v.u >> 16) & 1u);  // round-nearest-even
    return (unsigned short)(r >> 16);
}

// ---------------- prep: swizzled bf16 B operands into workspace -------------
// Per block, flat element e: j = e&7, lane = (e>>3)&63, qt = e>>9,
// t = qt % NT, q = qt / NT.  value = bf16(W[(q*32 + (lane>>4)*8 + j)*N
//                                          + t*16 + (lane&15)])
// Main kernel loads short8 at index (q*NT + t)*64 + lane (1KB/wave instr,
// L2-resident: 288KB total).
__global__ void prep_kernel(const float* __restrict__ w0,
                            const float* __restrict__ w1,
                            const float* __restrict__ w2,
                            unsigned short* __restrict__ ws) {
    int e = blockIdx.x * blockDim.x + threadIdx.x;
    const float* W; int N, base;
    if (e < 65536)       { W = w0; N = 256; base = 0; }
    else if (e < 131072) { W = w1; N = 256; base = 65536;  e -= 65536; }
    else if (e < 147456) { W = w2; N = 128; base = 131072; e -= 131072; }
    else return;
    int j = e & 7;
    int lane = (e >> 3) & 63;
    int qt = e >> 9;
    int NT = N >> 4;
    int t = qt % NT;
    int q = qt / NT;
    int u = q * 32 + ((lane >> 4) << 3) + j;
    int w = t * 16 + (lane & 15);
    ws[base + e] = f2bf(W[u * N + w]);
}

// ---------------- main kernel ----------------------------------------------
// D = irrep dim, K = mul (contraction), NT = total 16-wide w-tiles,
// NTW = w-tiles per wave (NT/4), OFF = column offset of this block.
// MFMA 16x16x32_bf16 layouts (HW-verified per guide):
//   A: lane holds A[m=lane&15][k=(lane>>4)*8+j]
//   B: lane holds B[k=(lane>>4)*8+j][n=lane&15]
//   C/D: reg r holds C[row=(lane>>4)*4+r][col=lane&15]
template<int D, int K, int NT, int NTW, int OFF>
__device__ __forceinline__ void run_block(const float* __restrict__ x,
                                          float* __restrict__ out,
                                          const short8* __restrict__ bsw,
                                          float pw, char* __restrict__ sm,
                                          int tile) {
    constexpr int COLS   = K * D;            // fp32 elems per row, this block
    constexpr int C4     = COLS / 4;         // float4 chunks per row
    constexpr int RB     = COLS * 2;         // LDS row stride, bytes (bf16)
    constexpr int ROUNDS = (16 * C4) / 256;  // stage rounds for 256 threads

    const int tid  = threadIdx.x;
    const int lane = tid & 63;
    const int wave = tid >> 6;

    float4 pf[ROUNDS];
    auto ld_pf = [&](int t) {
#pragma unroll
        for (int rr = 0; rr < ROUNDS; ++rr) {
            int c    = rr * 256 + tid;
            int row  = c / C4;          // compile-time-constant divisor
            int col4 = c - row * C4;
            pf[rr] = *((const float4*)
                       (x + (size_t)(t * 16 + row) * NTOTAL + OFF) + col4);
        }
    };
    // convert + write to XOR-swizzled LDS. RB % 128 == 0 for all blocks:
    // without the bit-4..6 XOR all 16 rows alias the same banks on the
    // b128 fragment reads.
    auto cvt_write = [&]() {
#pragma unroll
        for (int rr = 0; rr < ROUNDS; ++rr) {
            int c    = rr * 256 + tid;
            int row  = c / C4;
            int col4 = c - row * C4;
            float4 v = pf[rr];
            unsigned long long pk =
                  (unsigned long long)f2bf(v.x)
                | ((unsigned long long)f2bf(v.y) << 16)
                | ((unsigned long long)f2bf(v.z) << 32)
                | ((unsigned long long)f2bf(v.w) << 48);
            *(unsigned long long*)(sm + row * RB
                                   + ((col4 * 8) ^ ((row & 7) << 4))) = pk;
        }
    };

    // prologue: stage first tile (full __syncthreads is fine here)
    ld_pf(tile);
    cvt_write();
    __syncthreads();

    const int bcol = lane & 15;   // A row (m) / C col (n)
    const int quad = lane >> 4;
    const char* lrow = sm + bcol * RB;
    const int sw = (bcol & 7) << 4;

    while (true) {
        f32x4 acc[NTW][D];
#pragma unroll
        for (int tt = 0; tt < NTW; ++tt)
#pragma unroll
            for (int i = 0; i < D; ++i)
                acc[tt][i] = (f32x4){0.f, 0.f, 0.f, 0.f};

#pragma unroll
        for (int q = 0; q < K / 32; ++q) {
            // lane's 8*D consecutive bf16: D b128 reads, then stride-D repack
            const int cb = (q * 32 + quad * 8) * D * 2;   // multiple of 16
            short8 raw[D];
#pragma unroll
            for (int m = 0; m < D; ++m)
                raw[m] = *(const short8*)(lrow + ((cb + m * 16) ^ sw));

            short8 af[D];
#pragma unroll
            for (int i = 0; i < D; ++i)
#pragma unroll
                for (int j = 0; j < 8; ++j) {
                    const int e = j * D + i;
                    af[i][j] = raw[e >> 3][e & 7];
                }

#pragma unroll
            for (int tt = 0; tt < NTW; ++tt) {
                const int tw = wave * NTW + tt;
                short8 bf = bsw[(q * NT + tw) * 64 + lane];
#pragma unroll
                for (int i = 0; i < D; ++i)
                    acc[tt][i] = __builtin_amdgcn_mfma_f32_16x16x32_bf16(
                        af[i], bf, acc[tt][i], 0, 0, 0);
            }
        }

        const int nxt  = tile + GRIDX;
        const bool more = nxt < NTILES;   // WG-uniform

        // issue next tile's HBM loads strictly AFTER all B loads (vmcnt is
        // FIFO: pf ahead of B-frag loads would stall every MFMA on HBM).
        __builtin_amdgcn_sched_barrier(0);
        if (more) ld_pf(nxt);
        __builtin_amdgcn_sched_barrier(0);

        // epilogue stores overlap the pf latency:
        // y[b0+quad*4+r][OFF + (tw*16+bcol)*D + i] = pw * acc
        const int b0 = tile << 4;
#pragma unroll
        for (int tt = 0; tt < NTW; ++tt) {
            const int wcol = (wave * NTW + tt) * 16 + bcol;
#pragma unroll
            for (int r = 0; r < 4; ++r) {
                float* op = out + (size_t)(b0 + quad * 4 + r) * NTOTAL + OFF
                            + wcol * D;
#pragma unroll
                for (int i = 0; i < D; ++i)
                    op[i] = acc[tt][i][r] * pw;
            }
        }

        if (!more) break;

        // read-drain barrier: lgkm only -- pf global loads stay in flight.
        // (Full __syncthreads here would vmcnt(0)-drain them = v2's serial
        // stall. All ds_read results are already consumed into registers.)
        asm volatile("s_waitcnt lgkmcnt(0)" ::: "memory");
        __builtin_amdgcn_s_barrier();
        __builtin_amdgcn_sched_barrier(0);

        cvt_write();          // counted vmcnt waits per round, then ds_write
        __syncthreads();      // writes visible to all waves; pf consumed
        tile = nxt;
    }
}

__global__ __launch_bounds__(256)
void linear_kernel(const float* __restrict__ x, float* __restrict__ out,
                   const unsigned short* __restrict__ ws) {
    // Actual use: block1 = 16 rows * 768 bf16 = 24576 B. Deliberately
    // padded to 48 KiB: 160/48 -> max 3 WGs/CU, which drops the register
    // allocator's occupancy target to 3 waves/EU (VGPR budget 170) and
    // eliminates the 6-waves/EU spill-to-scratch choice (v3/v4: VGPR=84,
    // ~390 MB scratch traffic). 24576 B LDS => 6 WGs/CU => spill.
    __shared__ __attribute__((aligned(16))) char sm[49152];
    const short8* bs0 = (const short8*)(ws);
    const short8* bs1 = (const short8*)(ws + 65536);
    const short8* bs2 = (const short8*)(ws + 131072);
    if (blockIdx.y == 0)
        run_block<1, 256, 16, 4, 0>(x, out, bs0, 0.0625f, sm, blockIdx.x);
    else if (blockIdx.y == 1)
        run_block<3, 256, 16, 4, 256>(x, out, bs1, 0.0625f, sm, blockIdx.x);
    else
        run_block<5, 128, 8, 2, 1024>(x, out, bs2, 0.08838834764831845f, sm,
                                      blockIdx.x);
}

extern "C" void kernel_launch(void* const* d_in, const int* in_sizes, int n_in,
                              void* d_out, int out_size, void* d_ws,
                              size_t ws_size, hipStream_t stream) {
    const float* x  = (const float*)d_in[0];
    const float* w0 = (const float*)d_in[1];
    const float* w1 = (const float*)d_in[2];
    const float* w2 = (const float*)d_in[3];
    unsigned short* ws = (unsigned short*)d_ws;  // needs 294912 B

    prep_kernel<<<dim3(576), 256, 0, stream>>>(w0, w1, w2, ws);

    dim3 grid(GRIDX, 3);
    linear_kernel<<<grid, 256, 0, stream>>>(x, (float*)d_out, ws);
}

// Round 6
// 544.740 us; speedup vs baseline: 1.3505x; 1.0285x over previous
//
#include <hip/hip_runtime.h>

// Linear_6983616824492: e3nn-style irrep linear, B=50000, blocks (mul,d):
// (256,1)@off0, (256,3)@off256, (128,5)@off1024, row = 1664 fp32.
// v6: B-operand-in-registers persistent WGs. v2 (serial) and v5 (pipelined)
// both measured ~145-150 us vs the 106 us copy-ceiling floor; the shared
// cause is read-outstanding duty ~73%: per-iteration B-fragment global
// loads forbid issuing the x-prefetch before the K-loop (vmcnt is FIFO --
// a B wait would drain the older pf), so reads are in flight only during
// the short epilogue+barrier window. Fix: 16-wave (1024-thread) WGs, one
// w-tile per wave -> the wave's whole B operand is K/32 short8 = 32 VGPRs,
// loaded ONCE in the prologue. Steady state: cvt_write(pf)->sync->
// ld_pf(next)->compute(ds_read+MFMA only, no vmcnt waits)->stores->
// lgkm-barrier. pf stays outstanding under the entire compute phase.
// 256 persistent blocks (40/118/98 per y, proportional to traffic ->
// equal WG durations), 1 block/CU. Spill-guard: launch_bounds(1024,4) +
// waves_per_eu(4,4): at >64 VGPR a second resident block is impossible,
// so the allocator gains nothing by spilling (v3/v4 failure mode).
// Stage math, XOR swizzle, fragment repack, MFMA layouts, epilogue math:
// identical to the verified v2/v5 lineage.

typedef __attribute__((ext_vector_type(8))) short short8;   // 8 bf16 (4 VGPRs)
typedef __attribute__((ext_vector_type(4))) float f32x4;    // MFMA C/D frag

#define NBATCH 50000
#define NTOTAL 1664

__device__ __forceinline__ unsigned short f2bf(float f) {
    union { float f; unsigned u; } v; v.f = f;
    unsigned r = v.u + 0x7fffu + ((v.u >> 16) & 1u);  // round-nearest-even
    return (unsigned short)(r >> 16);
}

// ---------------- prep: swizzled bf16 B operands into workspace -------------
// Per block, flat element e: j = e&7, lane = (e>>3)&63, qt = e>>9,
// t = qt % NT, q = qt / NT.  value = bf16(W[(q*32 + (lane>>4)*8 + j)*N
//                                          + t*16 + (lane&15)])
// Main kernel loads short8 at index (q*NT + t)*64 + lane (L2-resident,
// 288KB total; each wave loads its slice once into registers).
__global__ void prep_kernel(const float* __restrict__ w0,
                            const float* __restrict__ w1,
                            const float* __restrict__ w2,
                            unsigned short* __restrict__ ws) {
    int e = blockIdx.x * blockDim.x + threadIdx.x;
    const float* W; int N, base;
    if (e < 65536)       { W = w0; N = 256; base = 0; }
    else if (e < 131072) { W = w1; N = 256; base = 65536;  e -= 65536; }
    else if (e < 147456) { W = w2; N = 128; base = 131072; e -= 131072; }
    else return;
    int j = e & 7;
    int lane = (e >> 3) & 63;
    int qt = e >> 9;
    int NT = N >> 4;
    int t = qt % NT;
    int q = qt / NT;
    int u = q * 32 + ((lane >> 4) << 3) + j;
    int w = t * 16 + (lane & 15);
    ws[base + e] = f2bf(W[u * N + w]);
}

// ---------------- main kernel ----------------------------------------------
// D = irrep dim, K = mul, NT = 16-wide w-tiles, OFF = column offset,
// HALVES = 1 (16-row iters, 16 waves x 16 tiles) or 2 (32-row iters for
// NT=8: waves 0-7 -> rows 0-15, waves 8-15 -> rows 16-31).
// MFMA 16x16x32_bf16 layouts (HW-verified per guide):
//   A: lane holds A[m=lane&15][k=(lane>>4)*8+j]
//   B: lane holds B[k=(lane>>4)*8+j][n=lane&15]
//   C/D: reg r holds C[row=(lane>>4)*4+r][col=lane&15]
template<int D, int K, int NT, int OFF, int HALVES>
__device__ __forceinline__ void run_block(const float* __restrict__ x,
                                          float* __restrict__ out,
                                          const short8* __restrict__ bsw,
                                          float pw, char* __restrict__ sm,
                                          int wgidx, int nwg) {
    constexpr int COLS   = K * D;              // fp32 elems per row
    constexpr int C4     = COLS / 4;           // float4 chunks per row
    constexpr int RB     = COLS * 2;           // LDS row stride, bytes
    constexpr int ROWS   = 16 * HALVES;        // batch rows per iteration
    constexpr int ROUNDS = (ROWS * C4) / 1024; // stage rounds, 1024 threads
    constexpr int QMAX   = K / 32;
    constexpr int NITER  = (NBATCH + ROWS - 1) / ROWS;

    const int tid  = threadIdx.x;
    const int lane = tid & 63;
    const int w    = tid >> 6;
    const int tw   = (HALVES == 2) ? (w & (NT - 1)) : w;  // wave's w-tile
    const int half = (HALVES == 2) ? (w >> 3) : 0;        // row half

    float4 pf[ROUNDS];
    auto ld_pf = [&](int rb) {
#pragma unroll
        for (int rr = 0; rr < ROUNDS; ++rr) {
            int c    = rr * 1024 + tid;
            int row  = c / C4;          // compile-time-constant divisor
            int col4 = c - row * C4;
            int gr   = rb + row;
            if constexpr (HALVES == 2) {   // one partial tail tile (y2)
                if (gr < NBATCH)
                    pf[rr] = *((const float4*)
                               (x + (size_t)gr * NTOTAL + OFF) + col4);
                else
                    pf[rr] = (float4){0.f, 0.f, 0.f, 0.f};
            } else {
                pf[rr] = *((const float4*)
                           (x + (size_t)gr * NTOTAL + OFF) + col4);
            }
        }
    };
    // convert + write to XOR-swizzled LDS. RB % 128 == 0 for all blocks:
    // without the bit-4..6 XOR all rows alias the same banks on the b128
    // fragment reads. Read-side key (bcol&7) matches since row%8 == bcol%8.
    auto cvt_write = [&]() {
#pragma unroll
        for (int rr = 0; rr < ROUNDS; ++rr) {
            int c    = rr * 1024 + tid;
            int row  = c / C4;
            int col4 = c - row * C4;
            float4 v = pf[rr];
            unsigned long long pk =
                  (unsigned long long)f2bf(v.x)
                | ((unsigned long long)f2bf(v.y) << 16)
                | ((unsigned long long)f2bf(v.z) << 32)
                | ((unsigned long long)f2bf(v.w) << 48);
            *(unsigned long long*)(sm + row * RB
                                   + ((col4 * 8) ^ ((row & 7) << 4))) = pk;
        }
    };

    // ---- B operand: resident in registers for the whole kernel ----
    short8 breg[QMAX];
#pragma unroll
    for (int q = 0; q < QMAX; ++q)
        breg[q] = bsw[(q * NT + tw) * 64 + lane];

    int it = wgidx;
    ld_pf(it * ROWS);              // prologue prefetch

    const int bcol = lane & 15;    // A row (m) / C col (n)
    const int quad = lane >> 4;
    const char* lrow = sm + (half * 16 + bcol) * RB;
    const int sw = (bcol & 7) << 4;

    while (true) {
        cvt_write();               // counted vmcnt waits on pf only
        __syncthreads();

        const int nxt  = it + nwg;
        const bool more = nxt < NITER;        // WG-uniform
        if (more) ld_pf(nxt * ROWS);          // ONLY global reads in queue;
        __builtin_amdgcn_sched_barrier(0);    // outstanding through compute

        f32x4 acc[D];
#pragma unroll
        for (int i = 0; i < D; ++i)
            acc[i] = (f32x4){0.f, 0.f, 0.f, 0.f};

#pragma unroll
        for (int q = 0; q < QMAX; ++q) {
            // lane's 8*D consecutive bf16: D b128 reads, then stride-D repack
            const int cb = (q * 32 + quad * 8) * D * 2;   // multiple of 16
            short8 raw[D];
#pragma unroll
            for (int m = 0; m < D; ++m)
                raw[m] = *(const short8*)(lrow + ((cb + m * 16) ^ sw));

            short8 af[D];
#pragma unroll
            for (int i = 0; i < D; ++i)
#pragma unroll
                for (int j = 0; j < 8; ++j) {
                    const int e = j * D + i;
                    af[i][j] = raw[e >> 3][e & 7];
                }

#pragma unroll
            for (int i = 0; i < D; ++i)
                acc[i] = __builtin_amdgcn_mfma_f32_16x16x32_bf16(
                    af[i], breg[q], acc[i], 0, 0, 0);
        }

        // epilogue: y[b0+quad*4+r][OFF + (tw*16+bcol)*D + i] = pw * acc
        const int b0   = it * ROWS + half * 16;
        const int wcol = tw * 16 + bcol;
#pragma unroll
        for (int r = 0; r < 4; ++r) {
            const int grow = b0 + quad * 4 + r;
            if constexpr (HALVES == 2) {
                if (grow >= NBATCH) continue;   // partial tail tile only
            }
            float* op = out + (size_t)grow * NTOTAL + OFF + wcol * D;
#pragma unroll
            for (int i = 0; i < D; ++i)
                op[i] = acc[i][r] * pw;
        }

        if (!more) break;

        // read-drain barrier: lgkm only -- pf global loads stay in flight.
        asm volatile("s_waitcnt lgkmcnt(0)" ::: "memory");
        __builtin_amdgcn_s_barrier();
        __builtin_amdgcn_sched_barrier(0);
        it = nxt;
    }
}

// 256 persistent blocks, 1024 threads (16 waves), 1 block/CU.
// launch_bounds(1024,4): 4 waves/EU min -> VGPR cap 128 (need ~115);
// waves_per_eu(4,4): exact -- no occupancy incentive to spill (v3/v4 trap).
__global__ __attribute__((amdgpu_waves_per_eu(4, 4)))
__launch_bounds__(1024, 4)
void linear_kernel(const float* __restrict__ x, float* __restrict__ out,
                   const unsigned short* __restrict__ ws) {
    // max actual LDS: y2 = 32 rows * 640 bf16 = 40960 B
    __shared__ __attribute__((aligned(16))) char sm[40960];
    const short8* bs0 = (const short8*)(ws);
    const short8* bs1 = (const short8*)(ws + 65536);
    const short8* bs2 = (const short8*)(ws + 131072);
    const int b = blockIdx.x;
    // WG counts proportional to per-y traffic (15.4% / 46.2% / 38.5%)
    // -> equal per-WG byte totals (~2.53 MB) -> balanced durations.
    if (b < 40)
        run_block<1, 256, 16, 0, 1>(x, out, bs0, 0.0625f, sm, b, 40);
    else if (b < 158)
        run_block<3, 256, 16, 256, 1>(x, out, bs1, 0.0625f, sm, b - 40, 118);
    else
        run_block<5, 128, 8, 1024, 2>(x, out, bs2, 0.08838834764831845f, sm,
                                      b - 158, 98);
}

extern "C" void kernel_launch(void* const* d_in, const int* in_sizes, int n_in,
                              void* d_out, int out_size, void* d_ws,
                              size_t ws_size, hipStream_t stream) {
    const float* x  = (const float*)d_in[0];
    const float* w0 = (const float*)d_in[1];
    const float* w1 = (const float*)d_in[2];
    const float* w2 = (const float*)d_in[3];
    unsigned short* ws = (unsigned short*)d_ws;  // needs 294912 B

    prep_kernel<<<dim3(576), 256, 0, stream>>>(w0, w1, w2, ws);

    linear_kernel<<<dim3(256), 1024, 0, stream>>>(x, (float*)d_out, ws);
}